// Round 4
// baseline (955.187 us; speedup 1.0000x reference)
//
#include <hip/hip_runtime.h>
#include <hip/hip_bf16.h>

#define DIV_UP(a,b) (((a)+(b)-1)/(b))

// ---------------- preprocessing: degree, dinv, CSR-by-dst ----------------

__global__ __launch_bounds__(256) void k_count(const int* __restrict__ dst, int* __restrict__ counts, int E){
  int e = blockIdx.x*256 + threadIdx.x;
  if (e < E) atomicAdd(&counts[dst[e]], 1);
}

__global__ __launch_bounds__(256) void k_dinv(const int* __restrict__ counts, float* __restrict__ dinv, int N){
  int n = blockIdx.x*256 + threadIdx.x;
  if (n < N) dinv[n] = rsqrtf((float)(counts[n] + 1));  // +1 = self-loop
}

__global__ __launch_bounds__(1024) void k_scan1(const int* __restrict__ counts, int* __restrict__ rowptr,
                                                int* __restrict__ bsum, int N){
  __shared__ int s[1024];
  int t = threadIdx.x, g = blockIdx.x*1024 + t;
  int v = (g < N) ? counts[g] : 0;
  s[t] = v; __syncthreads();
  for (int off = 1; off < 1024; off <<= 1){
    int u = (t >= off) ? s[t-off] : 0; __syncthreads();
    s[t] += u; __syncthreads();
  }
  if (g < N) rowptr[g] = s[t] - v;           // block-local exclusive scan
  if (t == 1023) bsum[blockIdx.x] = s[1023];
}

__global__ __launch_bounds__(128) void k_scan2(const int* __restrict__ bsum, int* __restrict__ boff,
                                               int nb, int* __restrict__ rowptr, int N){
  __shared__ int s[128];
  int t = threadIdx.x;
  int v = (t < nb) ? bsum[t] : 0;
  s[t] = v; __syncthreads();
  for (int off = 1; off < 128; off <<= 1){
    int u = (t >= off) ? s[t-off] : 0; __syncthreads();
    s[t] += u; __syncthreads();
  }
  if (t < nb) boff[t] = s[t] - v;            // exclusive over block sums
  if (t == 127) rowptr[N] = s[127];          // total = E
}

__global__ __launch_bounds__(1024) void k_scan3(int* __restrict__ rowptr, const int* __restrict__ boff, int N){
  int g = blockIdx.x*1024 + threadIdx.x;
  if (g < N) rowptr[g] += boff[blockIdx.x];
}

__global__ __launch_bounds__(256) void k_fill(const int* __restrict__ src, const int* __restrict__ dst,
                                              const int* __restrict__ rowptr, int* __restrict__ fill,
                                              int* __restrict__ csr, int E){
  int e = blockIdx.x*256 + threadIdx.x;
  if (e < E){
    int d = dst[e];
    int pos = rowptr[d] + atomicAdd(&fill[d], 1);
    csr[pos] = src[e];
  }
}

// ---------------- fused 64-wide aggregation of raw x (16 lanes/node, unroll-8) ----------------
__global__ __launch_bounds__(256) void k_agg64x(const float* __restrict__ x, const int* __restrict__ rowptr,
                                                const int* __restrict__ csr, const float* __restrict__ dinv,
                                                float* __restrict__ out, int N){
  const int tid = threadIdx.x;
  const int node = blockIdx.x*16 + (tid >> 4);
  if (node >= N) return;
  const int c = (tid & 15) * 4;
  const float* xc = x + c;
  const float dn = dinv[node];
  float4 s = *(const float4*)(x + (size_t)node*64 + c);
  float ax = dn*s.x, ay = dn*s.y, az = dn*s.z, aw = dn*s.w;  // self term
  int e = rowptr[node], end = rowptr[node+1];
  for (; e + 8 <= end; e += 8){
    int idx[8]; float dd[8]; float4 v[8];
    #pragma unroll
    for (int j = 0; j < 8; ++j) idx[j] = csr[e+j];
    #pragma unroll
    for (int j = 0; j < 8; ++j) dd[j] = dinv[idx[j]];
    #pragma unroll
    for (int j = 0; j < 8; ++j) v[j] = *(const float4*)(xc + (size_t)idx[j]*64);
    #pragma unroll
    for (int j = 0; j < 8; ++j){
      ax += dd[j]*v[j].x; ay += dd[j]*v[j].y; az += dd[j]*v[j].z; aw += dd[j]*v[j].w;
    }
  }
  for (; e + 4 <= end; e += 4){
    int s0 = csr[e], s1 = csr[e+1], s2 = csr[e+2], s3 = csr[e+3];
    float d0 = dinv[s0], d1 = dinv[s1], d2 = dinv[s2], d3 = dinv[s3];
    float4 v0 = *(const float4*)(xc + (size_t)s0*64);
    float4 v1 = *(const float4*)(xc + (size_t)s1*64);
    float4 v2 = *(const float4*)(xc + (size_t)s2*64);
    float4 v3 = *(const float4*)(xc + (size_t)s3*64);
    ax += d0*v0.x + d1*v1.x + d2*v2.x + d3*v3.x;
    ay += d0*v0.y + d1*v1.y + d2*v2.y + d3*v3.y;
    az += d0*v0.z + d1*v1.z + d2*v2.z + d3*v3.z;
    aw += d0*v0.w + d1*v1.w + d2*v2.w + d3*v3.w;
  }
  for (; e < end; ++e){
    int s0 = csr[e];
    float d0 = dinv[s0];
    float4 v = *(const float4*)(xc + (size_t)s0*64);
    ax += d0*v.x; ay += d0*v.y; az += d0*v.z; aw += d0*v.w;
  }
  float4 o = {dn*ax, dn*ay, dn*az, dn*aw};
  *(float4*)(out + (size_t)node*64 + c) = o;
}

// ---------------- GEMM: out[N,128] = H[N,FIN] @ W[FIN,128]; wave-uniform-B, scalar loads ----------------
// 64 rows/block, 128 threads (2 waves); lane = row, wave = 64-column half; B via s_load (uniform),
// A via 1 ds_read_b32 per kk. VALU-bound by design.
template<int FIN>
__global__ __launch_bounds__(128) void k_gemm_u(const float* __restrict__ H, const float* __restrict__ W,
                                                const float* __restrict__ bias, const float* __restrict__ dinv,
                                                float* __restrict__ out, int N, int relu){
  constexpr int KC = 32;
  __shared__ float At[KC][65];    // At[k][row], +1 pad
  const int tid = threadIdx.x;
  const int lane = tid & 63;
  const int wv = __builtin_amdgcn_readfirstlane(tid >> 6);  // 0 or 1 (wave-uniform)
  const int wcol = wv * 64;
  const int row0 = blockIdx.x * 64;
  const int row = row0 + lane;

  float4 acc[16];
  #pragma unroll
  for (int j = 0; j < 16; ++j) acc[j] = make_float4(0.f,0.f,0.f,0.f);

  for (int k0 = 0; k0 < FIN; k0 += KC){
    // stage A transposed (coalesced read; LDS write banks 2-way, free)
    #pragma unroll
    for (int it = 0; it < 4; ++it){
      int idx = it*128 + tid;      // 0..511
      int rr = idx >> 3;           // 0..63
      int c4 = (idx & 7) * 4;      // 0..28
      int grow = row0 + rr; if (grow >= N) grow = N - 1;
      float4 v = *(const float4*)(H + (size_t)grow*FIN + k0 + c4);
      At[c4+0][rr] = v.x; At[c4+1][rr] = v.y; At[c4+2][rr] = v.z; At[c4+3][rr] = v.w;
    }
    __syncthreads();
    const float* Wk = W + (size_t)k0*128 + wcol;   // wave-uniform base
    #pragma unroll 4
    for (int kk = 0; kk < KC; ++kk){
      float a = At[kk][lane];
      const float* wr = Wk + (size_t)kk*128;
      #pragma unroll
      for (int j = 0; j < 16; ++j){
        float4 b = *(const float4*)(wr + 4*j);     // uniform -> s_load_dwordx4
        acc[j].x += a*b.x; acc[j].y += a*b.y; acc[j].z += a*b.z; acc[j].w += a*b.w;
      }
    }
    __syncthreads();
  }

  if (row < N){
    float sc = dinv ? dinv[row] : 1.f;
    float* op = out + (size_t)row*128 + wcol;
    #pragma unroll
    for (int j = 0; j < 16; ++j){
      float4 o = acc[j];
      o.x *= sc; o.y *= sc; o.z *= sc; o.w *= sc;
      if (bias){
        o.x += bias[wcol+4*j];   o.y += bias[wcol+4*j+1];
        o.z += bias[wcol+4*j+2]; o.w += bias[wcol+4*j+3];
      }
      if (relu){
        o.x = fmaxf(o.x,0.f); o.y = fmaxf(o.y,0.f);
        o.z = fmaxf(o.z,0.f); o.w = fmaxf(o.w,0.f);
      }
      *(float4*)(op + 4*j) = o;
    }
  }
}

// ---------------- 128-wide CSR aggregation (32 lanes/node, unroll-8) ----------------
__global__ __launch_bounds__(256) void k_agg128(const float* __restrict__ p, const int* __restrict__ rowptr,
                                                const int* __restrict__ csr, const float* __restrict__ dinv,
                                                const float* __restrict__ bias, float* __restrict__ out, int N){
  const int tid = threadIdx.x;
  const int node = blockIdx.x*8 + (tid >> 5);
  if (node >= N) return;
  const int c = (tid & 31) * 4;
  const float* pc = p + c;
  int e = rowptr[node], end = rowptr[node+1];
  float4 s = *(const float4*)(p + (size_t)node*128 + c);   // self term
  float ax = s.x, ay = s.y, az = s.z, aw = s.w;
  for (; e + 8 <= end; e += 8){
    int idx[8]; float4 v[8];
    #pragma unroll
    for (int j = 0; j < 8; ++j) idx[j] = csr[e+j];
    #pragma unroll
    for (int j = 0; j < 8; ++j) v[j] = *(const float4*)(pc + (size_t)idx[j]*128);
    #pragma unroll
    for (int j = 0; j < 8; ++j){ ax += v[j].x; ay += v[j].y; az += v[j].z; aw += v[j].w; }
  }
  for (; e + 4 <= end; e += 4){
    int s0 = csr[e], s1 = csr[e+1], s2 = csr[e+2], s3 = csr[e+3];
    float4 v0 = *(const float4*)(pc + (size_t)s0*128);
    float4 v1 = *(const float4*)(pc + (size_t)s1*128);
    float4 v2 = *(const float4*)(pc + (size_t)s2*128);
    float4 v3 = *(const float4*)(pc + (size_t)s3*128);
    ax += v0.x+v1.x+v2.x+v3.x; ay += v0.y+v1.y+v2.y+v3.y;
    az += v0.z+v1.z+v2.z+v3.z; aw += v0.w+v1.w+v2.w+v3.w;
  }
  for (; e < end; ++e){
    float4 v = *(const float4*)(pc + (size_t)csr[e]*128);
    ax += v.x; ay += v.y; az += v.z; aw += v.w;
  }
  float d = dinv[node];
  float4 o = {fmaxf(d*ax + bias[c],   0.f), fmaxf(d*ay + bias[c+1], 0.f),
              fmaxf(d*az + bias[c+2], 0.f), fmaxf(d*aw + bias[c+3], 0.f)};
  *(float4*)(out + (size_t)node*128 + c) = o;
}

// ---------------- last 128-wide agg fused with W3 projection (32 lanes/node, unroll-8) ----------------
__global__ __launch_bounds__(256) void k_agg_last(const float* __restrict__ p, const int* __restrict__ rowptr,
                                                  const int* __restrict__ csr, const float* __restrict__ dinv,
                                                  const float* __restrict__ bias, const float* __restrict__ W3,
                                                  float* __restrict__ p5, int N){
  const int tid = threadIdx.x;
  const int node = blockIdx.x*8 + (tid >> 5);
  if (node >= N) return;
  const int c = (tid & 31) * 4;
  const float* pc = p + c;
  int e = rowptr[node], end = rowptr[node+1];
  float4 s = *(const float4*)(p + (size_t)node*128 + c);
  float ax = s.x, ay = s.y, az = s.z, aw = s.w;
  for (; e + 8 <= end; e += 8){
    int idx[8]; float4 v[8];
    #pragma unroll
    for (int j = 0; j < 8; ++j) idx[j] = csr[e+j];
    #pragma unroll
    for (int j = 0; j < 8; ++j) v[j] = *(const float4*)(pc + (size_t)idx[j]*128);
    #pragma unroll
    for (int j = 0; j < 8; ++j){ ax += v[j].x; ay += v[j].y; az += v[j].z; aw += v[j].w; }
  }
  for (; e + 4 <= end; e += 4){
    int s0 = csr[e], s1 = csr[e+1], s2 = csr[e+2], s3 = csr[e+3];
    float4 v0 = *(const float4*)(pc + (size_t)s0*128);
    float4 v1 = *(const float4*)(pc + (size_t)s1*128);
    float4 v2 = *(const float4*)(pc + (size_t)s2*128);
    float4 v3 = *(const float4*)(pc + (size_t)s3*128);
    ax += v0.x+v1.x+v2.x+v3.x; ay += v0.y+v1.y+v2.y+v3.y;
    az += v0.z+v1.z+v2.z+v3.z; aw += v0.w+v1.w+v2.w+v3.w;
  }
  for (; e < end; ++e){
    float4 v = *(const float4*)(pc + (size_t)csr[e]*128);
    ax += v.x; ay += v.y; az += v.z; aw += v.w;
  }
  float d = dinv[node];
  float o0 = fmaxf(d*ax + bias[c],   0.f);
  float o1 = fmaxf(d*ay + bias[c+1], 0.f);
  float o2 = fmaxf(d*az + bias[c+2], 0.f);
  float o3 = fmaxf(d*aw + bias[c+3], 0.f);
  float4 w = *(const float4*)(W3 + c);
  float sdot = o0*w.x + o1*w.y + o2*w.z + o3*w.w;
  #pragma unroll
  for (int m = 16; m >= 1; m >>= 1) sdot += __shfl_xor(sdot, m, 32);
  if ((tid & 31) == 0) p5[node] = d * sdot;
}

// ---------------- final scalar aggregation (unroll-8) ----------------
__global__ __launch_bounds__(256) void k_agg1(const float* __restrict__ p5, const int* __restrict__ rowptr,
                                              const int* __restrict__ csr, const float* __restrict__ dinv,
                                              const float* __restrict__ b3, float* __restrict__ out, int N){
  int n = blockIdx.x*256 + threadIdx.x;
  if (n >= N) return;
  int e = rowptr[n], end = rowptr[n+1];
  float acc = p5[n];
  for (; e + 8 <= end; e += 8){
    int idx[8]; float v[8];
    #pragma unroll
    for (int j = 0; j < 8; ++j) idx[j] = csr[e+j];
    #pragma unroll
    for (int j = 0; j < 8; ++j) v[j] = p5[idx[j]];
    #pragma unroll
    for (int j = 0; j < 8; ++j) acc += v[j];
  }
  for (; e < end; ++e) acc += p5[csr[e]];
  out[n] = dinv[n]*acc + b3[0];
}

extern "C" void kernel_launch(void* const* d_in, const int* in_sizes, int n_in,
                              void* d_out, int out_size, void* d_ws, size_t ws_size,
                              hipStream_t stream){
  const float* x  = (const float*)d_in[0];
  const int*   ei = (const int*)  d_in[1];
  const float* W1 = (const float*)d_in[2];
  const float* b1 = (const float*)d_in[3];
  const float* W2 = (const float*)d_in[4];
  const float* b2 = (const float*)d_in[5];
  const float* W3 = (const float*)d_in[6];
  const float* b3 = (const float*)d_in[7];
  float* out = (float*)d_out;

  const int N = in_sizes[0] / 64;
  const int E = in_sizes[1] / 2;
  const int L = in_sizes[4] / (128*128);
  const int* src = ei;
  const int* dst = ei + E;

  char* ws = (char*)d_ws;
  size_t off = 0;
  auto alloc = [&](size_t bytes){ void* p = ws + off; off += (bytes + 255) & ~(size_t)255; return p; };
  int*   counts = (int*)  alloc((size_t)N*4);
  int*   fillc  = (int*)  alloc((size_t)N*4);
  int*   rowptr = (int*)  alloc((size_t)(N+1)*4);
  int*   bsum   = (int*)  alloc(128*4);
  int*   boff   = (int*)  alloc(128*4);
  float* dinv   = (float*)alloc((size_t)N*4);
  float* p5     = (float*)alloc((size_t)N*4);
  int*   csr    = (int*)  alloc((size_t)E*4);
  float* bufA   = (float*)alloc((size_t)N*128*4);
  float* bufB   = (float*)alloc((size_t)N*128*4);
  (void)ws_size; (void)n_in; (void)out_size;

  hipMemsetAsync(counts, 0, (size_t)N*4, stream);
  hipMemsetAsync(fillc,  0, (size_t)N*4, stream);

  k_count<<<DIV_UP(E,256),256,0,stream>>>(dst, counts, E);
  k_dinv <<<DIV_UP(N,256),256,0,stream>>>(counts, dinv, N);
  int nb = DIV_UP(N,1024);
  k_scan1<<<nb,1024,0,stream>>>(counts, rowptr, bsum, N);
  k_scan2<<<1,128,0,stream>>>(bsum, boff, nb, rowptr, N);
  k_scan3<<<nb,1024,0,stream>>>(rowptr, boff, N);
  k_fill <<<DIV_UP(E,256),256,0,stream>>>(src, dst, rowptr, fillc, csr, E);

  // layer 1: aggregate raw x (64-wide, dinv fused), then GEMM 64->128 with bias+relu
  k_agg64x<<<DIV_UP(N,16),256,0,stream>>>(x, rowptr, csr, dinv, bufB, N);
  k_gemm_u<64><<<DIV_UP(N,64),128,0,stream>>>(bufB, W1, b1, nullptr, bufA, N, 1);

  // layers 2..4: GEMM (p = dinv*(h@W)), then gather-agg (+bias+relu); last agg fuses W3 projection
  for (int i = 0; i < L; ++i){
    k_gemm_u<128><<<DIV_UP(N,64),128,0,stream>>>(bufA, W2 + (size_t)i*128*128, nullptr, dinv, bufB, N, 0);
    if (i < L-1)
      k_agg128<<<DIV_UP(N,8),256,0,stream>>>(bufB, rowptr, csr, dinv, b2 + (size_t)i*128, bufA, N);
    else
      k_agg_last<<<DIV_UP(N,8),256,0,stream>>>(bufB, rowptr, csr, dinv, b2 + (size_t)i*128, W3, p5, N);
  }

  // output layer: scalar gather of p5
  k_agg1<<<DIV_UP(N,256),256,0,stream>>>(p5, rowptr, csr, dinv, b3, out, N);
}

// Round 5
// 918.557 us; speedup vs baseline: 1.0399x; 1.0399x over previous
//
#include <hip/hip_runtime.h>
#include <hip/hip_bf16.h>

#define DIV_UP(a,b) (((a)+(b)-1)/(b))

typedef __attribute__((ext_vector_type(8))) short short8v;
typedef __attribute__((ext_vector_type(4))) float f32x4;

__device__ inline unsigned short f2bf(float f){
  unsigned u = __float_as_uint(f);
  u += 0x7FFFu + ((u >> 16) & 1u);          // RNE
  return (unsigned short)(u >> 16);
}
__device__ inline float bf2f(unsigned short h){ return __uint_as_float(((unsigned)h) << 16); }

// ---------------- preprocessing: degree, dinv, CSR-by-dst ----------------

__global__ __launch_bounds__(256) void k_count(const int* __restrict__ dst, int* __restrict__ counts, int E){
  int e = blockIdx.x*256 + threadIdx.x;
  if (e < E) atomicAdd(&counts[dst[e]], 1);
}

__global__ __launch_bounds__(256) void k_dinv(const int* __restrict__ counts, float* __restrict__ dinv, int N){
  int n = blockIdx.x*256 + threadIdx.x;
  if (n < N) dinv[n] = rsqrtf((float)(counts[n] + 1));  // +1 = self-loop
}

__global__ __launch_bounds__(1024) void k_scan1(const int* __restrict__ counts, int* __restrict__ rowptr,
                                                int* __restrict__ bsum, int N){
  __shared__ int s[1024];
  int t = threadIdx.x, g = blockIdx.x*1024 + t;
  int v = (g < N) ? counts[g] : 0;
  s[t] = v; __syncthreads();
  for (int off = 1; off < 1024; off <<= 1){
    int u = (t >= off) ? s[t-off] : 0; __syncthreads();
    s[t] += u; __syncthreads();
  }
  if (g < N) rowptr[g] = s[t] - v;
  if (t == 1023) bsum[blockIdx.x] = s[1023];
}

__global__ __launch_bounds__(128) void k_scan2(const int* __restrict__ bsum, int* __restrict__ boff,
                                               int nb, int* __restrict__ rowptr, int N){
  __shared__ int s[128];
  int t = threadIdx.x;
  int v = (t < nb) ? bsum[t] : 0;
  s[t] = v; __syncthreads();
  for (int off = 1; off < 128; off <<= 1){
    int u = (t >= off) ? s[t-off] : 0; __syncthreads();
    s[t] += u; __syncthreads();
  }
  if (t < nb) boff[t] = s[t] - v;
  if (t == 127) rowptr[N] = s[127];
}

__global__ __launch_bounds__(1024) void k_scan3(int* __restrict__ rowptr, const int* __restrict__ boff, int N){
  int g = blockIdx.x*1024 + threadIdx.x;
  if (g < N) rowptr[g] += boff[blockIdx.x];
}

__global__ __launch_bounds__(256) void k_fill(const int* __restrict__ src, const int* __restrict__ dst,
                                              const int* __restrict__ rowptr, int* __restrict__ fill,
                                              int* __restrict__ csr, int E){
  int e = blockIdx.x*256 + threadIdx.x;
  if (e < E){
    int d = dst[e];
    int pos = rowptr[d] + atomicAdd(&fill[d], 1);
    csr[pos] = src[e];
  }
}

// ---------------- split + transpose weights: W[K][128] -> WhT/WlT[128][K] (bf16) ----------------
// layout: idx < 64*128 -> W1; else W2 layer i. Writes n-major (row = output col n, stride K).
__global__ __launch_bounds__(256) void k_split_w(const float* __restrict__ W1, const float* __restrict__ W2,
                                                 unsigned short* __restrict__ W1hT, unsigned short* __restrict__ W1lT,
                                                 unsigned short* __restrict__ W2hT, unsigned short* __restrict__ W2lT,
                                                 int L){
  int idx = blockIdx.x*256 + threadIdx.x;
  int n1 = 64*128;
  if (idx < n1){
    int k = idx >> 7, n = idx & 127;
    float v = W1[idx];
    unsigned short hi = f2bf(v);
    W1hT[n*64 + k] = hi;
    W1lT[n*64 + k] = f2bf(v - bf2f(hi));
  } else {
    int idx2 = idx - n1;
    if (idx2 >= L*128*128) return;
    int i = idx2 >> 14;          // /16384
    int r = idx2 & 16383;
    int k = r >> 7, n = r & 127;
    float v = W2[idx2];
    unsigned short hi = f2bf(v);
    W2hT[i*16384 + n*128 + k] = hi;
    W2lT[i*16384 + n*128 + k] = f2bf(v - bf2f(hi));
  }
}

// ---------------- fused 64-wide aggregation of raw x -> split bf16 output ----------------
__global__ __launch_bounds__(256) void k_agg64x(const float* __restrict__ x, const int* __restrict__ rowptr,
                                                const int* __restrict__ csr, const float* __restrict__ dinv,
                                                unsigned short* __restrict__ oh, unsigned short* __restrict__ ol,
                                                int N){
  const int tid = threadIdx.x;
  const int node = blockIdx.x*16 + (tid >> 4);
  if (node >= N) return;
  const int c = (tid & 15) * 4;
  const float* xc = x + c;
  const float dn = dinv[node];
  float4 s = *(const float4*)(x + (size_t)node*64 + c);
  float ax = dn*s.x, ay = dn*s.y, az = dn*s.z, aw = dn*s.w;
  int e = rowptr[node], end = rowptr[node+1];
  for (; e + 4 <= end; e += 4){
    int s0 = csr[e], s1 = csr[e+1], s2 = csr[e+2], s3 = csr[e+3];
    float d0 = dinv[s0], d1 = dinv[s1], d2 = dinv[s2], d3 = dinv[s3];
    float4 v0 = *(const float4*)(xc + (size_t)s0*64);
    float4 v1 = *(const float4*)(xc + (size_t)s1*64);
    float4 v2 = *(const float4*)(xc + (size_t)s2*64);
    float4 v3 = *(const float4*)(xc + (size_t)s3*64);
    ax += d0*v0.x + d1*v1.x + d2*v2.x + d3*v3.x;
    ay += d0*v0.y + d1*v1.y + d2*v2.y + d3*v3.y;
    az += d0*v0.z + d1*v1.z + d2*v2.z + d3*v3.z;
    aw += d0*v0.w + d1*v1.w + d2*v2.w + d3*v3.w;
  }
  for (; e < end; ++e){
    int s0 = csr[e];
    float d0 = dinv[s0];
    float4 v = *(const float4*)(xc + (size_t)s0*64);
    ax += d0*v.x; ay += d0*v.y; az += d0*v.z; aw += d0*v.w;
  }
  float o[4] = {dn*ax, dn*ay, dn*az, dn*aw};
  ushort4 hh, hl;
  unsigned short* hp = (unsigned short*)&hh;
  unsigned short* lp = (unsigned short*)&hl;
  #pragma unroll
  for (int j = 0; j < 4; ++j){
    unsigned short hi = f2bf(o[j]);
    hp[j] = hi; lp[j] = f2bf(o[j] - bf2f(hi));
  }
  *(ushort4*)(oh + (size_t)node*64 + c) = hh;
  *(ushort4*)(ol + (size_t)node*64 + c) = hl;
}

// ---------------- MFMA GEMM: C[N,128] = (Ah+Al)[N,K] @ (Bh+Bl)[K,128] via bf16x2 split ----------------
// 256 thr = 4 waves; wave w: rows blockIdx*64+w*16, all 128 cols (8 n-tiles of 16).
// A frag: A[m=lane&15][k=quad*8+j] -> 16B contig from row-major [N][K].
// B frag: B[k=quad*8+j][n=lane&15] -> 16B contig from transposed BhT[n][K].
// EPI=0: outF[row] = dinv[row]*acc ; EPI=1: relu(acc+bias) -> split bf16 (outH,outL).
template<int K, int EPI>
__global__ __launch_bounds__(256) void k_gemm_m(const unsigned short* __restrict__ Ah,
                                                const unsigned short* __restrict__ Al,
                                                const unsigned short* __restrict__ BhT,
                                                const unsigned short* __restrict__ BlT,
                                                const float* __restrict__ bias, const float* __restrict__ dinv,
                                                float* __restrict__ outF,
                                                unsigned short* __restrict__ outH, unsigned short* __restrict__ outL,
                                                int N){
  const int tid  = threadIdx.x;
  const int wv   = tid >> 6;
  const int lane = tid & 63;
  const int quad = lane >> 4;
  const int tcol = lane & 15;
  const int row0 = blockIdx.x*64 + wv*16;

  int arow = row0 + tcol; if (arow >= N) arow = N - 1;
  const unsigned short* ahp = Ah + (size_t)arow*K + quad*8;
  const unsigned short* alp = Al + (size_t)arow*K + quad*8;

  f32x4 acc[8];
  #pragma unroll
  for (int t = 0; t < 8; ++t){ acc[t][0]=0.f; acc[t][1]=0.f; acc[t][2]=0.f; acc[t][3]=0.f; }

  #pragma unroll
  for (int kc = 0; kc < K/32; ++kc){
    short8v a_h = *(const short8v*)(ahp + kc*32);
    short8v a_l = *(const short8v*)(alp + kc*32);
    const unsigned short* bb = BhT + (size_t)tcol*K + kc*32 + quad*8;
    const unsigned short* bl = BlT + (size_t)tcol*K + kc*32 + quad*8;
    #pragma unroll
    for (int nt = 0; nt < 8; ++nt){
      short8v b_h = *(const short8v*)(bb + (size_t)nt*16*K);
      short8v b_l = *(const short8v*)(bl + (size_t)nt*16*K);
      acc[nt] = __builtin_amdgcn_mfma_f32_16x16x32_bf16(a_h, b_h, acc[nt], 0, 0, 0);
      acc[nt] = __builtin_amdgcn_mfma_f32_16x16x32_bf16(a_l, b_h, acc[nt], 0, 0, 0);
      acc[nt] = __builtin_amdgcn_mfma_f32_16x16x32_bf16(a_h, b_l, acc[nt], 0, 0, 0);
    }
  }

  // C/D layout: col = lane&15, row(in-tile) = quad*4 + reg  [verified m89/m91]
  float bvals[8];
  if (EPI == 1){
    #pragma unroll
    for (int nt = 0; nt < 8; ++nt) bvals[nt] = bias[nt*16 + tcol];
  }
  #pragma unroll
  for (int reg = 0; reg < 4; ++reg){
    int grow = row0 + quad*4 + reg;
    if (grow < N){
      if (EPI == 0){
        float sc = dinv[grow];
        float* op = outF + (size_t)grow*128 + tcol;
        #pragma unroll
        for (int nt = 0; nt < 8; ++nt) op[nt*16] = acc[nt][reg] * sc;
      } else {
        unsigned short* hp = outH + (size_t)grow*128 + tcol;
        unsigned short* lp = outL + (size_t)grow*128 + tcol;
        #pragma unroll
        for (int nt = 0; nt < 8; ++nt){
          float o = fmaxf(acc[nt][reg] + bvals[nt], 0.f);
          unsigned short hi = f2bf(o);
          hp[nt*16] = hi;
          lp[nt*16] = f2bf(o - bf2f(hi));
        }
      }
    }
  }
}

// ---------------- 128-wide CSR aggregation (32 lanes/node) -> split bf16 output ----------------
__global__ __launch_bounds__(256) void k_agg128(const float* __restrict__ p, const int* __restrict__ rowptr,
                                                const int* __restrict__ csr, const float* __restrict__ dinv,
                                                const float* __restrict__ bias,
                                                unsigned short* __restrict__ oh, unsigned short* __restrict__ ol,
                                                int N){
  const int tid = threadIdx.x;
  const int node = blockIdx.x*8 + (tid >> 5);
  if (node >= N) return;
  const int c = (tid & 31) * 4;
  const float* pc = p + c;
  int e = rowptr[node], end = rowptr[node+1];
  float4 s = *(const float4*)(p + (size_t)node*128 + c);
  float ax = s.x, ay = s.y, az = s.z, aw = s.w;
  for (; e + 4 <= end; e += 4){
    int s0 = csr[e], s1 = csr[e+1], s2 = csr[e+2], s3 = csr[e+3];
    float4 v0 = *(const float4*)(pc + (size_t)s0*128);
    float4 v1 = *(const float4*)(pc + (size_t)s1*128);
    float4 v2 = *(const float4*)(pc + (size_t)s2*128);
    float4 v3 = *(const float4*)(pc + (size_t)s3*128);
    ax += v0.x+v1.x+v2.x+v3.x; ay += v0.y+v1.y+v2.y+v3.y;
    az += v0.z+v1.z+v2.z+v3.z; aw += v0.w+v1.w+v2.w+v3.w;
  }
  for (; e < end; ++e){
    float4 v = *(const float4*)(pc + (size_t)csr[e]*128);
    ax += v.x; ay += v.y; az += v.z; aw += v.w;
  }
  float d = dinv[node];
  float o[4] = {fmaxf(d*ax + bias[c],   0.f), fmaxf(d*ay + bias[c+1], 0.f),
                fmaxf(d*az + bias[c+2], 0.f), fmaxf(d*aw + bias[c+3], 0.f)};
  ushort4 hh, hl;
  unsigned short* hp = (unsigned short*)&hh;
  unsigned short* lp = (unsigned short*)&hl;
  #pragma unroll
  for (int j = 0; j < 4; ++j){
    unsigned short hi = f2bf(o[j]);
    hp[j] = hi; lp[j] = f2bf(o[j] - bf2f(hi));
  }
  *(ushort4*)(oh + (size_t)node*128 + c) = hh;
  *(ushort4*)(ol + (size_t)node*128 + c) = hl;
}

// ---------------- last 128-wide agg fused with W3 projection (32 lanes/node) ----------------
__global__ __launch_bounds__(256) void k_agg_last(const float* __restrict__ p, const int* __restrict__ rowptr,
                                                  const int* __restrict__ csr, const float* __restrict__ dinv,
                                                  const float* __restrict__ bias, const float* __restrict__ W3,
                                                  float* __restrict__ p5, int N){
  const int tid = threadIdx.x;
  const int node = blockIdx.x*8 + (tid >> 5);
  if (node >= N) return;
  const int c = (tid & 31) * 4;
  const float* pc = p + c;
  int e = rowptr[node], end = rowptr[node+1];
  float4 s = *(const float4*)(p + (size_t)node*128 + c);
  float ax = s.x, ay = s.y, az = s.z, aw = s.w;
  for (; e + 4 <= end; e += 4){
    int s0 = csr[e], s1 = csr[e+1], s2 = csr[e+2], s3 = csr[e+3];
    float4 v0 = *(const float4*)(pc + (size_t)s0*128);
    float4 v1 = *(const float4*)(pc + (size_t)s1*128);
    float4 v2 = *(const float4*)(pc + (size_t)s2*128);
    float4 v3 = *(const float4*)(pc + (size_t)s3*128);
    ax += v0.x+v1.x+v2.x+v3.x; ay += v0.y+v1.y+v2.y+v3.y;
    az += v0.z+v1.z+v2.z+v3.z; aw += v0.w+v1.w+v2.w+v3.w;
  }
  for (; e < end; ++e){
    float4 v = *(const float4*)(pc + (size_t)csr[e]*128);
    ax += v.x; ay += v.y; az += v.z; aw += v.w;
  }
  float d = dinv[node];
  float o0 = fmaxf(d*ax + bias[c],   0.f);
  float o1 = fmaxf(d*ay + bias[c+1], 0.f);
  float o2 = fmaxf(d*az + bias[c+2], 0.f);
  float o3 = fmaxf(d*aw + bias[c+3], 0.f);
  float4 w = *(const float4*)(W3 + c);
  float sdot = o0*w.x + o1*w.y + o2*w.z + o3*w.w;
  #pragma unroll
  for (int m = 16; m >= 1; m >>= 1) sdot += __shfl_xor(sdot, m, 32);
  if ((tid & 31) == 0) p5[node] = d * sdot;
}

// ---------------- final scalar aggregation ----------------
__global__ __launch_bounds__(256) void k_agg1(const float* __restrict__ p5, const int* __restrict__ rowptr,
                                              const int* __restrict__ csr, const float* __restrict__ dinv,
                                              const float* __restrict__ b3, float* __restrict__ out, int N){
  int n = blockIdx.x*256 + threadIdx.x;
  if (n >= N) return;
  int e = rowptr[n], end = rowptr[n+1];
  float acc = p5[n];
  for (; e + 4 <= end; e += 4)
    acc += p5[csr[e]] + p5[csr[e+1]] + p5[csr[e+2]] + p5[csr[e+3]];
  for (; e < end; ++e) acc += p5[csr[e]];
  out[n] = dinv[n]*acc + b3[0];
}

extern "C" void kernel_launch(void* const* d_in, const int* in_sizes, int n_in,
                              void* d_out, int out_size, void* d_ws, size_t ws_size,
                              hipStream_t stream){
  const float* x  = (const float*)d_in[0];
  const int*   ei = (const int*)  d_in[1];
  const float* W1 = (const float*)d_in[2];
  const float* b1 = (const float*)d_in[3];
  const float* W2 = (const float*)d_in[4];
  const float* b2 = (const float*)d_in[5];
  const float* W3 = (const float*)d_in[6];
  const float* b3 = (const float*)d_in[7];
  float* out = (float*)d_out;

  const int N = in_sizes[0] / 64;
  const int E = in_sizes[1] / 2;
  const int L = in_sizes[4] / (128*128);
  const int* src = ei;
  const int* dst = ei + E;

  char* ws = (char*)d_ws;
  size_t off = 0;
  auto alloc = [&](size_t bytes){ void* p = ws + off; off += (bytes + 255) & ~(size_t)255; return p; };
  int*   counts = (int*)  alloc((size_t)N*4);
  int*   fillc  = (int*)  alloc((size_t)N*4);
  int*   rowptr = (int*)  alloc((size_t)(N+1)*4);
  int*   bsum   = (int*)  alloc(128*4);
  int*   boff   = (int*)  alloc(128*4);
  float* dinv   = (float*)alloc((size_t)N*4);
  float* p5     = (float*)alloc((size_t)N*4);
  int*   csr    = (int*)  alloc((size_t)E*4);
  float* pF     = (float*)alloc((size_t)N*128*4);          // fp32 GEMM output (gather target)
  unsigned short* hh = (unsigned short*)alloc((size_t)N*128*2);
  unsigned short* hl = (unsigned short*)alloc((size_t)N*128*2);
  unsigned short* W1hT = (unsigned short*)alloc(64*128*2);
  unsigned short* W1lT = (unsigned short*)alloc(64*128*2);
  unsigned short* W2hT = (unsigned short*)alloc((size_t)L*128*128*2);
  unsigned short* W2lT = (unsigned short*)alloc((size_t)L*128*128*2);
  // 64-wide split buffers alias pF (pF first written after they are consumed)
  unsigned short* hh0 = (unsigned short*)pF;
  unsigned short* hl0 = ((unsigned short*)pF) + (size_t)N*64;
  (void)ws_size; (void)n_in; (void)out_size;

  hipMemsetAsync(counts, 0, (size_t)N*4, stream);
  hipMemsetAsync(fillc,  0, (size_t)N*4, stream);

  k_count<<<DIV_UP(E,256),256,0,stream>>>(dst, counts, E);
  k_dinv <<<DIV_UP(N,256),256,0,stream>>>(counts, dinv, N);
  int nb = DIV_UP(N,1024);
  k_scan1<<<nb,1024,0,stream>>>(counts, rowptr, bsum, N);
  k_scan2<<<1,128,0,stream>>>(bsum, boff, nb, rowptr, N);
  k_scan3<<<nb,1024,0,stream>>>(rowptr, boff, N);
  k_fill <<<DIV_UP(E,256),256,0,stream>>>(src, dst, rowptr, fillc, csr, E);

  // weight split+transpose (tiny)
  int wtot = 64*128 + L*128*128;
  k_split_w<<<DIV_UP(wtot,256),256,0,stream>>>(W1, W2, W1hT, W1lT, W2hT, W2lT, L);

  // layer 1: aggregate raw x (split-bf16 out), MFMA GEMM 64->128 (+bias+relu, split-bf16 out)
  k_agg64x<<<DIV_UP(N,16),256,0,stream>>>(x, rowptr, csr, dinv, hh0, hl0, N);
  k_gemm_m<64,1><<<DIV_UP(N,64),256,0,stream>>>(hh0, hl0, W1hT, W1lT, b1, nullptr,
                                                nullptr, hh, hl, N);

  // layers 2..4: MFMA GEMM (p = dinv*(h@W), fp32 out), then gather-agg (split-bf16 out / W3 fuse)
  for (int i = 0; i < L; ++i){
    k_gemm_m<128,0><<<DIV_UP(N,64),256,0,stream>>>(hh, hl, W2hT + (size_t)i*128*128, W2lT + (size_t)i*128*128,
                                                   nullptr, dinv, pF, nullptr, nullptr, N);
    if (i < L-1)
      k_agg128<<<DIV_UP(N,8),256,0,stream>>>(pF, rowptr, csr, dinv, b2 + (size_t)i*128, hh, hl, N);
    else
      k_agg_last<<<DIV_UP(N,8),256,0,stream>>>(pF, rowptr, csr, dinv, b2 + (size_t)i*128, W3, p5, N);
  }

  // output layer: scalar gather of p5
  k_agg1<<<DIV_UP(N,256),256,0,stream>>>(p5, rowptr, csr, dinv, b3, out, N);
}

// Round 6
// 792.001 us; speedup vs baseline: 1.2060x; 1.1598x over previous
//
#include <hip/hip_runtime.h>
#include <hip/hip_bf16.h>

#define DIV_UP(a,b) (((a)+(b)-1)/(b))

typedef __attribute__((ext_vector_type(8))) short short8v;
typedef __attribute__((ext_vector_type(4))) float f32x4;

__device__ inline unsigned short f2bf(float f){
  unsigned u = __float_as_uint(f);
  u += 0x7FFFu + ((u >> 16) & 1u);          // RNE
  return (unsigned short)(u >> 16);
}
__device__ inline float bf2f(unsigned short h){ return __uint_as_float(((unsigned)h) << 16); }

// ---------------- preprocessing: degree, dinv, CSR-by-dst ----------------

__global__ __launch_bounds__(256) void k_count(const int* __restrict__ dst, int* __restrict__ counts, int E){
  int e = blockIdx.x*256 + threadIdx.x;
  if (e < E) atomicAdd(&counts[dst[e]], 1);
}

__global__ __launch_bounds__(256) void k_dinv(const int* __restrict__ counts, float* __restrict__ dinv, int N){
  int n = blockIdx.x*256 + threadIdx.x;
  if (n < N) dinv[n] = rsqrtf((float)(counts[n] + 1));  // +1 = self-loop
}

__global__ __launch_bounds__(1024) void k_scan1(const int* __restrict__ counts, int* __restrict__ rowptr,
                                                int* __restrict__ bsum, int N){
  __shared__ int s[1024];
  int t = threadIdx.x, g = blockIdx.x*1024 + t;
  int v = (g < N) ? counts[g] : 0;
  s[t] = v; __syncthreads();
  for (int off = 1; off < 1024; off <<= 1){
    int u = (t >= off) ? s[t-off] : 0; __syncthreads();
    s[t] += u; __syncthreads();
  }
  if (g < N) rowptr[g] = s[t] - v;
  if (t == 1023) bsum[blockIdx.x] = s[1023];
}

__global__ __launch_bounds__(128) void k_scan2(const int* __restrict__ bsum, int* __restrict__ boff,
                                               int nb, int* __restrict__ rowptr, int N){
  __shared__ int s[128];
  int t = threadIdx.x;
  int v = (t < nb) ? bsum[t] : 0;
  s[t] = v; __syncthreads();
  for (int off = 1; off < 128; off <<= 1){
    int u = (t >= off) ? s[t-off] : 0; __syncthreads();
    s[t] += u; __syncthreads();
  }
  if (t < nb) boff[t] = s[t] - v;
  if (t == 127) rowptr[N] = s[127];
}

__global__ __launch_bounds__(1024) void k_scan3(int* __restrict__ rowptr, const int* __restrict__ boff, int N){
  int g = blockIdx.x*1024 + threadIdx.x;
  if (g < N) rowptr[g] += boff[blockIdx.x];
}

__global__ __launch_bounds__(256) void k_fill(const int* __restrict__ src, const int* __restrict__ dst,
                                              const int* __restrict__ rowptr, int* __restrict__ fill,
                                              int* __restrict__ csr, int E){
  int e = blockIdx.x*256 + threadIdx.x;
  if (e < E){
    int d = dst[e];
    int pos = rowptr[d] + atomicAdd(&fill[d], 1);
    csr[pos] = src[e];
  }
}

// ---------------- split weights into FRAGMENT-LINEARIZED bf16 hi/lo ----------------
// Output index o = ((kc*8 + nt)*64 + lane)*8 + j  maps to  W[k][n], k = kc*32 + (lane>>4)*8 + j,
// n = nt*16 + (lane&15).  GEMM B-loads become wave-contiguous 1KB.
__global__ __launch_bounds__(256) void k_split_w(const float* __restrict__ W1, const float* __restrict__ W2,
                                                 unsigned short* __restrict__ W1h, unsigned short* __restrict__ W1l,
                                                 unsigned short* __restrict__ W2h, unsigned short* __restrict__ W2l,
                                                 int L){
  int idx = blockIdx.x*256 + threadIdx.x;
  int n1 = 64*128;
  if (idx < n1){
    int j = idx & 7, lane = (idx >> 3) & 63, t = idx >> 9;   // t = kc*8+nt, kc<2 (K=64)
    int kc = t >> 3, nt = t & 7;
    int tcol = lane & 15, quad = lane >> 4;
    int k = kc*32 + quad*8 + j, n = nt*16 + tcol;
    float v = W1[k*128 + n];
    unsigned short hi = f2bf(v);
    W1h[idx] = hi; W1l[idx] = f2bf(v - bf2f(hi));
  } else {
    int idx2 = idx - n1;
    if (idx2 >= L*128*128) return;
    int i = idx2 >> 14, r = idx2 & 16383;
    int j = r & 7, lane = (r >> 3) & 63, t = r >> 9;         // t = kc*8+nt, kc<4 (K=128)
    int kc = t >> 3, nt = t & 7;
    int tcol = lane & 15, quad = lane >> 4;
    int k = kc*32 + quad*8 + j, n = nt*16 + tcol;
    float v = W2[(size_t)i*16384 + k*128 + n];
    unsigned short hi = f2bf(v);
    W2h[idx2] = hi; W2l[idx2] = f2bf(v - bf2f(hi));
  }
}

// ---------------- fused 64-wide aggregation of raw x -> split bf16 output ----------------
__global__ __launch_bounds__(256) void k_agg64x(const float* __restrict__ x, const int* __restrict__ rowptr,
                                                const int* __restrict__ csr, const float* __restrict__ dinv,
                                                unsigned short* __restrict__ oh, unsigned short* __restrict__ ol,
                                                int N){
  const int tid = threadIdx.x;
  const int node = blockIdx.x*16 + (tid >> 4);
  if (node >= N) return;
  const int c = (tid & 15) * 4;
  const float* xc = x + c;
  const float dn = dinv[node];
  float4 s = *(const float4*)(x + (size_t)node*64 + c);
  float ax = dn*s.x, ay = dn*s.y, az = dn*s.z, aw = dn*s.w;
  int e = rowptr[node], end = rowptr[node+1];
  for (; e + 4 <= end; e += 4){
    int s0 = csr[e], s1 = csr[e+1], s2 = csr[e+2], s3 = csr[e+3];
    float d0 = dinv[s0], d1 = dinv[s1], d2 = dinv[s2], d3 = dinv[s3];
    float4 v0 = *(const float4*)(xc + (size_t)s0*64);
    float4 v1 = *(const float4*)(xc + (size_t)s1*64);
    float4 v2 = *(const float4*)(xc + (size_t)s2*64);
    float4 v3 = *(const float4*)(xc + (size_t)s3*64);
    ax += d0*v0.x + d1*v1.x + d2*v2.x + d3*v3.x;
    ay += d0*v0.y + d1*v1.y + d2*v2.y + d3*v3.y;
    az += d0*v0.z + d1*v1.z + d2*v2.z + d3*v3.z;
    aw += d0*v0.w + d1*v1.w + d2*v2.w + d3*v3.w;
  }
  for (; e < end; ++e){
    int s0 = csr[e];
    float d0 = dinv[s0];
    float4 v = *(const float4*)(xc + (size_t)s0*64);
    ax += d0*v.x; ay += d0*v.y; az += d0*v.z; aw += d0*v.w;
  }
  float o[4] = {dn*ax, dn*ay, dn*az, dn*aw};
  ushort4 hh, hl;
  unsigned short* hp = (unsigned short*)&hh;
  unsigned short* lp = (unsigned short*)&hl;
  #pragma unroll
  for (int j = 0; j < 4; ++j){
    unsigned short hi = f2bf(o[j]);
    hp[j] = hi; lp[j] = f2bf(o[j] - bf2f(hi));
  }
  *(ushort4*)(oh + (size_t)node*64 + c) = hh;
  *(ushort4*)(ol + (size_t)node*64 + c) = hl;
}

// ---------------- MFMA GEMM: C[N,128] = (Ah+Al)[N,K] @ (Bh+Bl)[K,128] via bf16x2 split ----------------
// 256 thr = 4 waves; wave w: rows blockIdx*64+w*16, all 128 cols (8 n-tiles of 16).
// A: row-major (2 scattered 16B loads / kc).  B: fragment-linearized (16 coalesced 1KB loads / kc, L1-hot).
// EPI=0: outF[row] = dinv[row]*acc ; EPI=1: relu(acc+bias) -> split bf16 (outH,outL).
template<int K, int EPI>
__global__ __launch_bounds__(256) void k_gemm_m(const unsigned short* __restrict__ Ah,
                                                const unsigned short* __restrict__ Al,
                                                const unsigned short* __restrict__ Bh,
                                                const unsigned short* __restrict__ Bl,
                                                const float* __restrict__ bias, const float* __restrict__ dinv,
                                                float* __restrict__ outF,
                                                unsigned short* __restrict__ outH, unsigned short* __restrict__ outL,
                                                int N){
  const int tid  = threadIdx.x;
  const int wv   = tid >> 6;
  const int lane = tid & 63;
  const int quad = lane >> 4;
  const int tcol = lane & 15;
  const int row0 = blockIdx.x*64 + wv*16;

  int arow = row0 + tcol; if (arow >= N) arow = N - 1;
  const unsigned short* ahp = Ah + (size_t)arow*K + quad*8;
  const unsigned short* alp = Al + (size_t)arow*K + quad*8;

  f32x4 acc[8];
  #pragma unroll
  for (int t = 0; t < 8; ++t){ acc[t][0]=0.f; acc[t][1]=0.f; acc[t][2]=0.f; acc[t][3]=0.f; }

  #pragma unroll
  for (int kc = 0; kc < K/32; ++kc){
    short8v a_h = *(const short8v*)(ahp + kc*32);
    short8v a_l = *(const short8v*)(alp + kc*32);
    const unsigned short* bb = Bh + ((size_t)(kc*8)*64 + lane)*8;
    const unsigned short* bl = Bl + ((size_t)(kc*8)*64 + lane)*8;
    #pragma unroll
    for (int nt = 0; nt < 8; ++nt){
      short8v b_h = *(const short8v*)(bb + (size_t)nt*512);   // 64 lanes * 8 shorts
      short8v b_l = *(const short8v*)(bl + (size_t)nt*512);
      acc[nt] = __builtin_amdgcn_mfma_f32_16x16x32_bf16(a_h, b_h, acc[nt], 0, 0, 0);
      acc[nt] = __builtin_amdgcn_mfma_f32_16x16x32_bf16(a_l, b_h, acc[nt], 0, 0, 0);
      acc[nt] = __builtin_amdgcn_mfma_f32_16x16x32_bf16(a_h, b_l, acc[nt], 0, 0, 0);
    }
  }

  // C/D layout: col = lane&15, row(in-tile) = quad*4 + reg
  float bvals[8];
  if (EPI == 1){
    #pragma unroll
    for (int nt = 0; nt < 8; ++nt) bvals[nt] = bias[nt*16 + tcol];
  }
  #pragma unroll
  for (int reg = 0; reg < 4; ++reg){
    int grow = row0 + quad*4 + reg;
    if (grow < N){
      if (EPI == 0){
        float sc = dinv[grow];
        float* op = outF + (size_t)grow*128 + tcol;
        #pragma unroll
        for (int nt = 0; nt < 8; ++nt) op[nt*16] = acc[nt][reg] * sc;
      } else {
        unsigned short* hp = outH + (size_t)grow*128 + tcol;
        unsigned short* lp = outL + (size_t)grow*128 + tcol;
        #pragma unroll
        for (int nt = 0; nt < 8; ++nt){
          float o = fmaxf(acc[nt][reg] + bvals[nt], 0.f);
          unsigned short hi = f2bf(o);
          hp[nt*16] = hi;
          lp[nt*16] = f2bf(o - bf2f(hi));
        }
      }
    }
  }
}

// ---------------- 128-wide CSR aggregation (32 lanes/node) -> split bf16 output ----------------
__global__ __launch_bounds__(256) void k_agg128(const float* __restrict__ p, const int* __restrict__ rowptr,
                                                const int* __restrict__ csr, const float* __restrict__ dinv,
                                                const float* __restrict__ bias,
                                                unsigned short* __restrict__ oh, unsigned short* __restrict__ ol,
                                                int N){
  const int tid = threadIdx.x;
  const int node = blockIdx.x*8 + (tid >> 5);
  if (node >= N) return;
  const int c = (tid & 31) * 4;
  const float* pc = p + c;
  int e = rowptr[node], end = rowptr[node+1];
  float4 s = *(const float4*)(p + (size_t)node*128 + c);
  float ax = s.x, ay = s.y, az = s.z, aw = s.w;
  for (; e + 4 <= end; e += 4){
    int s0 = csr[e], s1 = csr[e+1], s2 = csr[e+2], s3 = csr[e+3];
    float4 v0 = *(const float4*)(pc + (size_t)s0*128);
    float4 v1 = *(const float4*)(pc + (size_t)s1*128);
    float4 v2 = *(const float4*)(pc + (size_t)s2*128);
    float4 v3 = *(const float4*)(pc + (size_t)s3*128);
    ax += v0.x+v1.x+v2.x+v3.x; ay += v0.y+v1.y+v2.y+v3.y;
    az += v0.z+v1.z+v2.z+v3.z; aw += v0.w+v1.w+v2.w+v3.w;
  }
  for (; e < end; ++e){
    float4 v = *(const float4*)(pc + (size_t)csr[e]*128);
    ax += v.x; ay += v.y; az += v.z; aw += v.w;
  }
  float d = dinv[node];
  float o[4] = {fmaxf(d*ax + bias[c],   0.f), fmaxf(d*ay + bias[c+1], 0.f),
                fmaxf(d*az + bias[c+2], 0.f), fmaxf(d*aw + bias[c+3], 0.f)};
  ushort4 hh, hl;
  unsigned short* hp = (unsigned short*)&hh;
  unsigned short* lp = (unsigned short*)&hl;
  #pragma unroll
  for (int j = 0; j < 4; ++j){
    unsigned short hi = f2bf(o[j]);
    hp[j] = hi; lp[j] = f2bf(o[j] - bf2f(hi));
  }
  *(ushort4*)(oh + (size_t)node*128 + c) = hh;
  *(ushort4*)(ol + (size_t)node*128 + c) = hl;
}

// ---------------- last 128-wide agg fused with W3 projection (32 lanes/node) ----------------
__global__ __launch_bounds__(256) void k_agg_last(const float* __restrict__ p, const int* __restrict__ rowptr,
                                                  const int* __restrict__ csr, const float* __restrict__ dinv,
                                                  const float* __restrict__ bias, const float* __restrict__ W3,
                                                  float* __restrict__ p5, int N){
  const int tid = threadIdx.x;
  const int node = blockIdx.x*8 + (tid >> 5);
  if (node >= N) return;
  const int c = (tid & 31) * 4;
  const float* pc = p + c;
  int e = rowptr[node], end = rowptr[node+1];
  float4 s = *(const float4*)(p + (size_t)node*128 + c);
  float ax = s.x, ay = s.y, az = s.z, aw = s.w;
  for (; e + 4 <= end; e += 4){
    int s0 = csr[e], s1 = csr[e+1], s2 = csr[e+2], s3 = csr[e+3];
    float4 v0 = *(const float4*)(pc + (size_t)s0*128);
    float4 v1 = *(const float4*)(pc + (size_t)s1*128);
    float4 v2 = *(const float4*)(pc + (size_t)s2*128);
    float4 v3 = *(const float4*)(pc + (size_t)s3*128);
    ax += v0.x+v1.x+v2.x+v3.x; ay += v0.y+v1.y+v2.y+v3.y;
    az += v0.z+v1.z+v2.z+v3.z; aw += v0.w+v1.w+v2.w+v3.w;
  }
  for (; e < end; ++e){
    float4 v = *(const float4*)(pc + (size_t)csr[e]*128);
    ax += v.x; ay += v.y; az += v.z; aw += v.w;
  }
  float d = dinv[node];
  float o0 = fmaxf(d*ax + bias[c],   0.f);
  float o1 = fmaxf(d*ay + bias[c+1], 0.f);
  float o2 = fmaxf(d*az + bias[c+2], 0.f);
  float o3 = fmaxf(d*aw + bias[c+3], 0.f);
  float4 w = *(const float4*)(W3 + c);
  float sdot = o0*w.x + o1*w.y + o2*w.z + o3*w.w;
  #pragma unroll
  for (int m = 16; m >= 1; m >>= 1) sdot += __shfl_xor(sdot, m, 32);
  if ((tid & 31) == 0) p5[node] = d * sdot;
}

// ---------------- final scalar aggregation ----------------
__global__ __launch_bounds__(256) void k_agg1(const float* __restrict__ p5, const int* __restrict__ rowptr,
                                              const int* __restrict__ csr, const float* __restrict__ dinv,
                                              const float* __restrict__ b3, float* __restrict__ out, int N){
  int n = blockIdx.x*256 + threadIdx.x;
  if (n >= N) return;
  int e = rowptr[n], end = rowptr[n+1];
  float acc = p5[n];
  for (; e + 4 <= end; e += 4)
    acc += p5[csr[e]] + p5[csr[e+1]] + p5[csr[e+2]] + p5[csr[e+3]];
  for (; e < end; ++e) acc += p5[csr[e]];
  out[n] = dinv[n]*acc + b3[0];
}

extern "C" void kernel_launch(void* const* d_in, const int* in_sizes, int n_in,
                              void* d_out, int out_size, void* d_ws, size_t ws_size,
                              hipStream_t stream){
  const float* x  = (const float*)d_in[0];
  const int*   ei = (const int*)  d_in[1];
  const float* W1 = (const float*)d_in[2];
  const float* b1 = (const float*)d_in[3];
  const float* W2 = (const float*)d_in[4];
  const float* b2 = (const float*)d_in[5];
  const float* W3 = (const float*)d_in[6];
  const float* b3 = (const float*)d_in[7];
  float* out = (float*)d_out;

  const int N = in_sizes[0] / 64;
  const int E = in_sizes[1] / 2;
  const int L = in_sizes[4] / (128*128);
  const int* src = ei;
  const int* dst = ei + E;

  char* ws = (char*)d_ws;
  size_t off = 0;
  auto alloc = [&](size_t bytes){ void* p = ws + off; off += (bytes + 255) & ~(size_t)255; return p; };
  int*   counts = (int*)  alloc((size_t)N*4);
  int*   fillc  = (int*)  alloc((size_t)N*4);
  int*   rowptr = (int*)  alloc((size_t)(N+1)*4);
  int*   bsum   = (int*)  alloc(128*4);
  int*   boff   = (int*)  alloc(128*4);
  float* dinv   = (float*)alloc((size_t)N*4);
  float* p5     = (float*)alloc((size_t)N*4);
  int*   csr    = (int*)  alloc((size_t)E*4);
  float* pF     = (float*)alloc((size_t)N*128*4);          // fp32 GEMM output (gather target)
  unsigned short* hh = (unsigned short*)alloc((size_t)N*128*2);
  unsigned short* hl = (unsigned short*)alloc((size_t)N*128*2);
  unsigned short* W1h = (unsigned short*)alloc(64*128*2);
  unsigned short* W1l = (unsigned short*)alloc(64*128*2);
  unsigned short* W2h = (unsigned short*)alloc((size_t)L*128*128*2);
  unsigned short* W2l = (unsigned short*)alloc((size_t)L*128*128*2);
  // 64-wide split buffers alias pF (consumed before pF is first written)
  unsigned short* hh0 = (unsigned short*)pF;
  unsigned short* hl0 = ((unsigned short*)pF) + (size_t)N*64;
  (void)ws_size; (void)n_in; (void)out_size;

  hipMemsetAsync(counts, 0, (size_t)N*4, stream);
  hipMemsetAsync(fillc,  0, (size_t)N*4, stream);

  k_count<<<DIV_UP(E,256),256,0,stream>>>(dst, counts, E);
  k_dinv <<<DIV_UP(N,256),256,0,stream>>>(counts, dinv, N);
  int nb = DIV_UP(N,1024);
  k_scan1<<<nb,1024,0,stream>>>(counts, rowptr, bsum, N);
  k_scan2<<<1,128,0,stream>>>(bsum, boff, nb, rowptr, N);
  k_scan3<<<nb,1024,0,stream>>>(rowptr, boff, N);
  k_fill <<<DIV_UP(E,256),256,0,stream>>>(src, dst, rowptr, fillc, csr, E);

  // weight split into fragment-linearized bf16 hi/lo (tiny)
  int wtot = 64*128 + L*128*128;
  k_split_w<<<DIV_UP(wtot,256),256,0,stream>>>(W1, W2, W1h, W1l, W2h, W2l, L);

  // layer 1: aggregate raw x (split-bf16 out), MFMA GEMM 64->128 (+bias+relu, split-bf16 out)
  k_agg64x<<<DIV_UP(N,16),256,0,stream>>>(x, rowptr, csr, dinv, hh0, hl0, N);
  k_gemm_m<64,1><<<DIV_UP(N,64),256,0,stream>>>(hh0, hl0, W1h, W1l, b1, nullptr,
                                                nullptr, hh, hl, N);

  // layers 2..4: MFMA GEMM (p = dinv*(h@W), fp32 out), then gather-agg (split-bf16 out / W3 fuse)
  for (int i = 0; i < L; ++i){
    k_gemm_m<128,0><<<DIV_UP(N,64),256,0,stream>>>(hh, hl, W2h + (size_t)i*128*128, W2l + (size_t)i*128*128,
                                                   nullptr, dinv, pF, nullptr, nullptr, N);
    if (i < L-1)
      k_agg128<<<DIV_UP(N,8),256,0,stream>>>(pF, rowptr, csr, dinv, b2 + (size_t)i*128, hh, hl, N);
    else
      k_agg_last<<<DIV_UP(N,8),256,0,stream>>>(pF, rowptr, csr, dinv, b2 + (size_t)i*128, W3, p5, N);
  }

  // output layer: scalar gather of p5
  k_agg1<<<DIV_UP(N,256),256,0,stream>>>(p5, rowptr, csr, dinv, b3, out, N);
}

// Round 7
// 762.586 us; speedup vs baseline: 1.2526x; 1.0386x over previous
//
#include <hip/hip_runtime.h>
#include <hip/hip_bf16.h>

#define DIV_UP(a,b) (((a)+(b)-1)/(b))

typedef __attribute__((ext_vector_type(8))) short short8v;
typedef __attribute__((ext_vector_type(4))) float f32x4;

__device__ inline unsigned short f2bf(float f){
  unsigned u = __float_as_uint(f);
  u += 0x7FFFu + ((u >> 16) & 1u);          // RNE
  return (unsigned short)(u >> 16);
}
__device__ inline float bf2f(unsigned short h){ return __uint_as_float(((unsigned)h) << 16); }

// ---------------- preprocessing: degree, dinv, CSR-by-dst (XCD-grouped) ----------------
// Blocks partitioned into 8 groups via blockIdx&7 (round-robin -> XCD heuristic).
// Group g only processes edges with dst in its N/8 slice: atomics + scatter writes stay
// in one L2 (50 KB counts slice / ~800 KB csr slice), killing the 16x write amplification.

__global__ __launch_bounds__(256) void k_count_g(const int* __restrict__ dst, int* __restrict__ counts,
                                                 int E, int N){
  const int g   = blockIdx.x & 7;
  const int bi  = blockIdx.x >> 3;
  const int bpg = gridDim.x >> 3;
  const int chunk = (N + 7) >> 3;
  const int lo = g*chunk;
  const int hi = min(lo + chunk, N);
  for (int e = bi*256 + threadIdx.x; e < E; e += bpg*256){
    int d = dst[e];
    if (d >= lo && d < hi) atomicAdd(&counts[d], 1);
  }
}

__global__ __launch_bounds__(256) void k_fill_g(const int* __restrict__ src, const int* __restrict__ dst,
                                                const int* __restrict__ rowptr, int* __restrict__ fill,
                                                int* __restrict__ csr, int E, int N){
  const int g   = blockIdx.x & 7;
  const int bi  = blockIdx.x >> 3;
  const int bpg = gridDim.x >> 3;
  const int chunk = (N + 7) >> 3;
  const int lo = g*chunk;
  const int hi = min(lo + chunk, N);
  for (int e = bi*256 + threadIdx.x; e < E; e += bpg*256){
    int d = dst[e];
    if (d >= lo && d < hi){
      int pos = rowptr[d] + atomicAdd(&fill[d], 1);
      csr[pos] = src[e];
    }
  }
}

__global__ __launch_bounds__(1024) void k_scan1(const int* __restrict__ counts, int* __restrict__ rowptr,
                                                int* __restrict__ bsum, float* __restrict__ dinv, int N){
  __shared__ int s[1024];
  int t = threadIdx.x, g = blockIdx.x*1024 + t;
  int v = (g < N) ? counts[g] : 0;
  if (g < N) dinv[g] = rsqrtf((float)(v + 1));   // +1 = self-loop (folded former k_dinv)
  s[t] = v; __syncthreads();
  for (int off = 1; off < 1024; off <<= 1){
    int u = (t >= off) ? s[t-off] : 0; __syncthreads();
    s[t] += u; __syncthreads();
  }
  if (g < N) rowptr[g] = s[t] - v;
  if (t == 1023) bsum[blockIdx.x] = s[1023];
}

__global__ __launch_bounds__(128) void k_scan2(const int* __restrict__ bsum, int* __restrict__ boff,
                                               int nb, int* __restrict__ rowptr, int N){
  __shared__ int s[128];
  int t = threadIdx.x;
  int v = (t < nb) ? bsum[t] : 0;
  s[t] = v; __syncthreads();
  for (int off = 1; off < 128; off <<= 1){
    int u = (t >= off) ? s[t-off] : 0; __syncthreads();
    s[t] += u; __syncthreads();
  }
  if (t < nb) boff[t] = s[t] - v;
  if (t == 127) rowptr[N] = s[127];
}

__global__ __launch_bounds__(1024) void k_scan3(int* __restrict__ rowptr, const int* __restrict__ boff, int N){
  int g = blockIdx.x*1024 + threadIdx.x;
  if (g < N) rowptr[g] += boff[blockIdx.x];
}

// ---------------- split weights into FRAGMENT-LINEARIZED bf16 hi/lo ----------------
__global__ __launch_bounds__(256) void k_split_w(const float* __restrict__ W1, const float* __restrict__ W2,
                                                 unsigned short* __restrict__ W1h, unsigned short* __restrict__ W1l,
                                                 unsigned short* __restrict__ W2h, unsigned short* __restrict__ W2l,
                                                 int L){
  int idx = blockIdx.x*256 + threadIdx.x;
  int n1 = 64*128;
  if (idx < n1){
    int j = idx & 7, lane = (idx >> 3) & 63, t = idx >> 9;   // t = kc*8+nt, kc<2 (K=64)
    int kc = t >> 3, nt = t & 7;
    int tcol = lane & 15, quad = lane >> 4;
    int k = kc*32 + quad*8 + j, n = nt*16 + tcol;
    float v = W1[k*128 + n];
    unsigned short hi = f2bf(v);
    W1h[idx] = hi; W1l[idx] = f2bf(v - bf2f(hi));
  } else {
    int idx2 = idx - n1;
    if (idx2 >= L*128*128) return;
    int i = idx2 >> 14, r = idx2 & 16383;
    int j = r & 7, lane = (r >> 3) & 63, t = r >> 9;         // t = kc*8+nt, kc<4 (K=128)
    int kc = t >> 3, nt = t & 7;
    int tcol = lane & 15, quad = lane >> 4;
    int k = kc*32 + quad*8 + j, n = nt*16 + tcol;
    float v = W2[(size_t)i*16384 + k*128 + n];
    unsigned short hi = f2bf(v);
    W2h[idx2] = hi; W2l[idx2] = f2bf(v - bf2f(hi));
  }
}

// ---------------- fused 64-wide aggregation of raw x -> split bf16 output ----------------
__global__ __launch_bounds__(256) void k_agg64x(const float* __restrict__ x, const int* __restrict__ rowptr,
                                                const int* __restrict__ csr, const float* __restrict__ dinv,
                                                unsigned short* __restrict__ oh, unsigned short* __restrict__ ol,
                                                int N){
  const int tid = threadIdx.x;
  const int node = blockIdx.x*16 + (tid >> 4);
  if (node >= N) return;
  const int c = (tid & 15) * 4;
  const float* xc = x + c;
  const float dn = dinv[node];
  float4 s = *(const float4*)(x + (size_t)node*64 + c);
  float ax = dn*s.x, ay = dn*s.y, az = dn*s.z, aw = dn*s.w;
  int e = rowptr[node], end = rowptr[node+1];
  for (; e + 4 <= end; e += 4){
    int s0 = csr[e], s1 = csr[e+1], s2 = csr[e+2], s3 = csr[e+3];
    float d0 = dinv[s0], d1 = dinv[s1], d2 = dinv[s2], d3 = dinv[s3];
    float4 v0 = *(const float4*)(xc + (size_t)s0*64);
    float4 v1 = *(const float4*)(xc + (size_t)s1*64);
    float4 v2 = *(const float4*)(xc + (size_t)s2*64);
    float4 v3 = *(const float4*)(xc + (size_t)s3*64);
    ax += d0*v0.x + d1*v1.x + d2*v2.x + d3*v3.x;
    ay += d0*v0.y + d1*v1.y + d2*v2.y + d3*v3.y;
    az += d0*v0.z + d1*v1.z + d2*v2.z + d3*v3.z;
    aw += d0*v0.w + d1*v1.w + d2*v2.w + d3*v3.w;
  }
  for (; e < end; ++e){
    int s0 = csr[e];
    float d0 = dinv[s0];
    float4 v = *(const float4*)(xc + (size_t)s0*64);
    ax += d0*v.x; ay += d0*v.y; az += d0*v.z; aw += d0*v.w;
  }
  float o[4] = {dn*ax, dn*ay, dn*az, dn*aw};
  ushort4 hh, hl;
  unsigned short* hp = (unsigned short*)&hh;
  unsigned short* lp = (unsigned short*)&hl;
  #pragma unroll
  for (int j = 0; j < 4; ++j){
    unsigned short hi = f2bf(o[j]);
    hp[j] = hi; lp[j] = f2bf(o[j] - bf2f(hi));
  }
  *(ushort4*)(oh + (size_t)node*64 + c) = hh;
  *(ushort4*)(ol + (size_t)node*64 + c) = hl;
}

// ---------------- MFMA GEMM: C[N,128] = (Ah+Al)[N,K] @ (Bh+Bl)[K,128] via bf16x2 split ----------------
template<int K, int EPI>
__global__ __launch_bounds__(256) void k_gemm_m(const unsigned short* __restrict__ Ah,
                                                const unsigned short* __restrict__ Al,
                                                const unsigned short* __restrict__ Bh,
                                                const unsigned short* __restrict__ Bl,
                                                const float* __restrict__ bias, const float* __restrict__ dinv,
                                                float* __restrict__ outF,
                                                unsigned short* __restrict__ outH, unsigned short* __restrict__ outL,
                                                int N){
  const int tid  = threadIdx.x;
  const int wv   = tid >> 6;
  const int lane = tid & 63;
  const int quad = lane >> 4;
  const int tcol = lane & 15;
  const int row0 = blockIdx.x*64 + wv*16;

  int arow = row0 + tcol; if (arow >= N) arow = N - 1;
  const unsigned short* ahp = Ah + (size_t)arow*K + quad*8;
  const unsigned short* alp = Al + (size_t)arow*K + quad*8;

  f32x4 acc[8];
  #pragma unroll
  for (int t = 0; t < 8; ++t){ acc[t][0]=0.f; acc[t][1]=0.f; acc[t][2]=0.f; acc[t][3]=0.f; }

  #pragma unroll
  for (int kc = 0; kc < K/32; ++kc){
    short8v a_h = *(const short8v*)(ahp + kc*32);
    short8v a_l = *(const short8v*)(alp + kc*32);
    const unsigned short* bb = Bh + ((size_t)(kc*8)*64 + lane)*8;
    const unsigned short* bl = Bl + ((size_t)(kc*8)*64 + lane)*8;
    #pragma unroll
    for (int nt = 0; nt < 8; ++nt){
      short8v b_h = *(const short8v*)(bb + (size_t)nt*512);   // 64 lanes * 8 shorts
      short8v b_l = *(const short8v*)(bl + (size_t)nt*512);
      acc[nt] = __builtin_amdgcn_mfma_f32_16x16x32_bf16(a_h, b_h, acc[nt], 0, 0, 0);
      acc[nt] = __builtin_amdgcn_mfma_f32_16x16x32_bf16(a_l, b_h, acc[nt], 0, 0, 0);
      acc[nt] = __builtin_amdgcn_mfma_f32_16x16x32_bf16(a_h, b_l, acc[nt], 0, 0, 0);
    }
  }

  // C/D layout: col = lane&15, row(in-tile) = quad*4 + reg
  float bvals[8];
  if (EPI == 1){
    #pragma unroll
    for (int nt = 0; nt < 8; ++nt) bvals[nt] = bias[nt*16 + tcol];
  }
  #pragma unroll
  for (int reg = 0; reg < 4; ++reg){
    int grow = row0 + quad*4 + reg;
    if (grow < N){
      if (EPI == 0){
        float sc = dinv[grow];
        float* op = outF + (size_t)grow*128 + tcol;
        #pragma unroll
        for (int nt = 0; nt < 8; ++nt) op[nt*16] = acc[nt][reg] * sc;
      } else {
        unsigned short* hp = outH + (size_t)grow*128 + tcol;
        unsigned short* lp = outL + (size_t)grow*128 + tcol;
        #pragma unroll
        for (int nt = 0; nt < 8; ++nt){
          float o = fmaxf(acc[nt][reg] + bvals[nt], 0.f);
          unsigned short hi = f2bf(o);
          hp[nt*16] = hi;
          lp[nt*16] = f2bf(o - bf2f(hi));
        }
      }
    }
  }
}

// ---------------- 128-wide CSR aggregation (32 lanes/node) -> split bf16 output ----------------
__global__ __launch_bounds__(256) void k_agg128(const float* __restrict__ p, const int* __restrict__ rowptr,
                                                const int* __restrict__ csr, const float* __restrict__ dinv,
                                                const float* __restrict__ bias,
                                                unsigned short* __restrict__ oh, unsigned short* __restrict__ ol,
                                                int N){
  const int tid = threadIdx.x;
  const int node = blockIdx.x*8 + (tid >> 5);
  if (node >= N) return;
  const int c = (tid & 31) * 4;
  const float* pc = p + c;
  int e = rowptr[node], end = rowptr[node+1];
  float4 s = *(const float4*)(p + (size_t)node*128 + c);
  float ax = s.x, ay = s.y, az = s.z, aw = s.w;
  for (; e + 4 <= end; e += 4){
    int s0 = csr[e], s1 = csr[e+1], s2 = csr[e+2], s3 = csr[e+3];
    float4 v0 = *(const float4*)(pc + (size_t)s0*128);
    float4 v1 = *(const float4*)(pc + (size_t)s1*128);
    float4 v2 = *(const float4*)(pc + (size_t)s2*128);
    float4 v3 = *(const float4*)(pc + (size_t)s3*128);
    ax += v0.x+v1.x+v2.x+v3.x; ay += v0.y+v1.y+v2.y+v3.y;
    az += v0.z+v1.z+v2.z+v3.z; aw += v0.w+v1.w+v2.w+v3.w;
  }
  for (; e < end; ++e){
    float4 v = *(const float4*)(pc + (size_t)csr[e]*128);
    ax += v.x; ay += v.y; az += v.z; aw += v.w;
  }
  float d = dinv[node];
  float o[4] = {fmaxf(d*ax + bias[c],   0.f), fmaxf(d*ay + bias[c+1], 0.f),
                fmaxf(d*az + bias[c+2], 0.f), fmaxf(d*aw + bias[c+3], 0.f)};
  ushort4 hh, hl;
  unsigned short* hp = (unsigned short*)&hh;
  unsigned short* lp = (unsigned short*)&hl;
  #pragma unroll
  for (int j = 0; j < 4; ++j){
    unsigned short hi = f2bf(o[j]);
    hp[j] = hi; lp[j] = f2bf(o[j] - bf2f(hi));
  }
  *(ushort4*)(oh + (size_t)node*128 + c) = hh;
  *(ushort4*)(ol + (size_t)node*128 + c) = hl;
}

// ---------------- last 128-wide agg fused with W3 projection (32 lanes/node) ----------------
__global__ __launch_bounds__(256) void k_agg_last(const float* __restrict__ p, const int* __restrict__ rowptr,
                                                  const int* __restrict__ csr, const float* __restrict__ dinv,
                                                  const float* __restrict__ bias, const float* __restrict__ W3,
                                                  float* __restrict__ p5, int N){
  const int tid = threadIdx.x;
  const int node = blockIdx.x*8 + (tid >> 5);
  if (node >= N) return;
  const int c = (tid & 31) * 4;
  const float* pc = p + c;
  int e = rowptr[node], end = rowptr[node+1];
  float4 s = *(const float4*)(p + (size_t)node*128 + c);
  float ax = s.x, ay = s.y, az = s.z, aw = s.w;
  for (; e + 4 <= end; e += 4){
    int s0 = csr[e], s1 = csr[e+1], s2 = csr[e+2], s3 = csr[e+3];
    float4 v0 = *(const float4*)(pc + (size_t)s0*128);
    float4 v1 = *(const float4*)(pc + (size_t)s1*128);
    float4 v2 = *(const float4*)(pc + (size_t)s2*128);
    float4 v3 = *(const float4*)(pc + (size_t)s3*128);
    ax += v0.x+v1.x+v2.x+v3.x; ay += v0.y+v1.y+v2.y+v3.y;
    az += v0.z+v1.z+v2.z+v3.z; aw += v0.w+v1.w+v2.w+v3.w;
  }
  for (; e < end; ++e){
    float4 v = *(const float4*)(pc + (size_t)csr[e]*128);
    ax += v.x; ay += v.y; az += v.z; aw += v.w;
  }
  float d = dinv[node];
  float o0 = fmaxf(d*ax + bias[c],   0.f);
  float o1 = fmaxf(d*ay + bias[c+1], 0.f);
  float o2 = fmaxf(d*az + bias[c+2], 0.f);
  float o3 = fmaxf(d*aw + bias[c+3], 0.f);
  float4 w = *(const float4*)(W3 + c);
  float sdot = o0*w.x + o1*w.y + o2*w.z + o3*w.w;
  #pragma unroll
  for (int m = 16; m >= 1; m >>= 1) sdot += __shfl_xor(sdot, m, 32);
  if ((tid & 31) == 0) p5[node] = d * sdot;
}

// ---------------- final scalar aggregation ----------------
__global__ __launch_bounds__(256) void k_agg1(const float* __restrict__ p5, const int* __restrict__ rowptr,
                                              const int* __restrict__ csr, const float* __restrict__ dinv,
                                              const float* __restrict__ b3, float* __restrict__ out, int N){
  int n = blockIdx.x*256 + threadIdx.x;
  if (n >= N) return;
  int e = rowptr[n], end = rowptr[n+1];
  float acc = p5[n];
  for (; e + 4 <= end; e += 4)
    acc += p5[csr[e]] + p5[csr[e+1]] + p5[csr[e+2]] + p5[csr[e+3]];
  for (; e < end; ++e) acc += p5[csr[e]];
  out[n] = dinv[n]*acc + b3[0];
}

extern "C" void kernel_launch(void* const* d_in, const int* in_sizes, int n_in,
                              void* d_out, int out_size, void* d_ws, size_t ws_size,
                              hipStream_t stream){
  const float* x  = (const float*)d_in[0];
  const int*   ei = (const int*)  d_in[1];
  const float* W1 = (const float*)d_in[2];
  const float* b1 = (const float*)d_in[3];
  const float* W2 = (const float*)d_in[4];
  const float* b2 = (const float*)d_in[5];
  const float* W3 = (const float*)d_in[6];
  const float* b3 = (const float*)d_in[7];
  float* out = (float*)d_out;

  const int N = in_sizes[0] / 64;
  const int E = in_sizes[1] / 2;
  const int L = in_sizes[4] / (128*128);
  const int* src = ei;
  const int* dst = ei + E;

  char* ws = (char*)d_ws;
  size_t off = 0;
  auto alloc = [&](size_t bytes){ void* p = ws + off; off += (bytes + 255) & ~(size_t)255; return p; };
  size_t cntb = ((size_t)N*4 + 255) & ~(size_t)255;
  int*   counts = (int*)  alloc(cntb*2);       // counts + fillc, adjacent -> one memset
  int*   fillc  = (int*)((char*)counts + cntb);
  int*   rowptr = (int*)  alloc((size_t)(N+1)*4);
  int*   bsum   = (int*)  alloc(128*4);
  int*   boff   = (int*)  alloc(128*4);
  float* dinv   = (float*)alloc((size_t)N*4);
  float* p5     = (float*)alloc((size_t)N*4);
  int*   csr    = (int*)  alloc((size_t)E*4);
  float* pF     = (float*)alloc((size_t)N*128*4);          // fp32 GEMM output (gather target)
  unsigned short* hh = (unsigned short*)alloc((size_t)N*128*2);
  unsigned short* hl = (unsigned short*)alloc((size_t)N*128*2);
  unsigned short* W1h = (unsigned short*)alloc(64*128*2);
  unsigned short* W1l = (unsigned short*)alloc(64*128*2);
  unsigned short* W2h = (unsigned short*)alloc((size_t)L*128*128*2);
  unsigned short* W2l = (unsigned short*)alloc((size_t)L*128*128*2);
  // 64-wide split buffers alias pF (consumed before pF is first written)
  unsigned short* hh0 = (unsigned short*)pF;
  unsigned short* hl0 = ((unsigned short*)pF) + (size_t)N*64;
  (void)ws_size; (void)n_in; (void)out_size;

  hipMemsetAsync(counts, 0, cntb*2, stream);

  k_count_g<<<1024,256,0,stream>>>(dst, counts, E, N);
  int nb = DIV_UP(N,1024);
  k_scan1<<<nb,1024,0,stream>>>(counts, rowptr, bsum, dinv, N);
  k_scan2<<<1,128,0,stream>>>(bsum, boff, nb, rowptr, N);
  k_scan3<<<nb,1024,0,stream>>>(rowptr, boff, N);
  k_fill_g<<<1024,256,0,stream>>>(src, dst, rowptr, fillc, csr, E, N);

  // weight split into fragment-linearized bf16 hi/lo (tiny)
  int wtot = 64*128 + L*128*128;
  k_split_w<<<DIV_UP(wtot,256),256,0,stream>>>(W1, W2, W1h, W1l, W2h, W2l, L);

  // layer 1: aggregate raw x (split-bf16 out), MFMA GEMM 64->128 (+bias+relu, split-bf16 out)
  k_agg64x<<<DIV_UP(N,16),256,0,stream>>>(x, rowptr, csr, dinv, hh0, hl0, N);
  k_gemm_m<64,1><<<DIV_UP(N,64),256,0,stream>>>(hh0, hl0, W1h, W1l, b1, nullptr,
                                                nullptr, hh, hl, N);

  // layers 2..4: MFMA GEMM (p = dinv*(h@W), fp32 out), then gather-agg (split-bf16 out / W3 fuse)
  for (int i = 0; i < L; ++i){
    k_gemm_m<128,0><<<DIV_UP(N,64),256,0,stream>>>(hh, hl, W2h + (size_t)i*128*128, W2l + (size_t)i*128*128,
                                                   nullptr, dinv, pF, nullptr, nullptr, N);
    if (i < L-1)
      k_agg128<<<DIV_UP(N,8),256,0,stream>>>(pF, rowptr, csr, dinv, b2 + (size_t)i*128, hh, hl, N);
    else
      k_agg_last<<<DIV_UP(N,8),256,0,stream>>>(pF, rowptr, csr, dinv, b2 + (size_t)i*128, W3, p5, N);
  }

  // output layer: scalar gather of p5
  k_agg1<<<DIV_UP(N,256),256,0,stream>>>(p5, rowptr, csr, dinv, b3, out, N);
}